// Round 8
// baseline (1605.313 us; speedup 1.0000x reference)
//
#include <hip/hip_runtime.h>
#include <hip/hip_bf16.h>

// GCNConv: out = relu( D^{-1/2} (A + I) D^{-1/2} (x @ W) + b )
// CSR-free: bucket sort (bucket = dst>>7) then fused LDS-accumulator aggregate.
//   1. k_hist   : per-block LDS histograms -> hist[bucket][block] (+ Wt convert)
//   2. scanA/B/C2: exclusive scan of hist (in place) -> write bases
//   3. k_scatter: edges -> bucket-grouped packed array (src | dlow<<17)
//   4. k_deg    : per-bucket degree -> dinv = rsqrt(deg+1)
//   5. k_gemm   : xs = bf16( dinv[n] * (x[n] @ W) ) MFMA; xs stored PERMUTED:
//                 bf16 position p = (f%16)*8 + f/16   (f = feature index)
//   6. k_agg    : one 1024-thr block per bucket; 67.6 KB LDS fp32 acc[128][132];
//                 streams bucket edges (+128 synthetic self-edges) in static
//                 16-gather sweeps; LDS atomic adds (consecutive-bank layout);
//                 epilogue: out = relu(dinv*acc + b), coalesced fp32 stores.

#define SCAN_BLK 256
#define NP1 160          // blocks in phase-1 (hist/scatter); M=B*NP1 scan <=512*256
#define MAXB 1024        // static LDS cap on bucket count (N <= 131072)

typedef short  short8 __attribute__((ext_vector_type(8)));
typedef float  f32x4  __attribute__((ext_vector_type(4)));

__device__ inline unsigned short f2b(float f) {   // fp32 -> bf16 RNE
    unsigned u = __float_as_uint(f);
    return (unsigned short)((u + 0x7fffu + ((u >> 16) & 1u)) >> 16);
}

__device__ inline float blo(unsigned u) { return __uint_as_float(u << 16); }
__device__ inline float bhi(unsigned u) { return __uint_as_float(u & 0xffff0000u); }

// ---- phase 1: bucket histogram (+ fused Wt = bf16(W^T)) -----------------
__global__ __launch_bounds__(256) void k_hist(const int* __restrict__ dst,
                                              int* __restrict__ hist,
                                              const float* __restrict__ W,
                                              unsigned short* __restrict__ Wt,
                                              int E, int B, int chunk) {
    __shared__ int h[MAXB];
    for (int i = threadIdx.x; i < B; i += 256) h[i] = 0;
    __syncthreads();
    int e0 = blockIdx.x * chunk;
    int e1 = min(E, e0 + chunk);
    for (int e = e0 + threadIdx.x; e < e1; e += 256)
        atomicAdd(&h[dst[e] >> 7], 1);
    __syncthreads();
    for (int i = threadIdx.x; i < B; i += 256)
        hist[i * NP1 + blockIdx.x] = h[i];
    if (blockIdx.x < 64) {                      // fused weight transpose
        int i = blockIdx.x * 256 + threadIdx.x; // 0..16383
        int k = i >> 7, n = i & 127;
        Wt[n * 128 + k] = f2b(W[k * 128 + n]);
    }
}

// ---- generic exclusive scan over M ints ---------------------------------
__global__ __launch_bounds__(SCAN_BLK) void k_scanA(const int* __restrict__ in,
                                                    int* __restrict__ bsum, int M) {
    __shared__ int s[SCAN_BLK];
    int t = threadIdx.x;
    int i = blockIdx.x * SCAN_BLK + t;
    s[t] = (i < M) ? in[i] : 0;
    __syncthreads();
    for (int off = SCAN_BLK / 2; off > 0; off >>= 1) {
        if (t < off) s[t] += s[t + off];
        __syncthreads();
    }
    if (t == 0) bsum[blockIdx.x] = s[0];
}

__global__ __launch_bounds__(512) void k_scanB(int* __restrict__ bsum, int nb) {
    __shared__ int s[512];
    int t = threadIdx.x;
    int v = (t < nb) ? bsum[t] : 0;
    s[t] = v;
    __syncthreads();
    for (int off = 1; off < 512; off <<= 1) {
        int add = (t >= off) ? s[t - off] : 0;
        __syncthreads();
        s[t] += add;
        __syncthreads();
    }
    if (t < nb) bsum[t] = s[t] - v;   // exclusive
}

// in-place safe: each element read+written only by its own block
__global__ __launch_bounds__(SCAN_BLK) void k_scanC2(int* __restrict__ data,
                                                     const int* __restrict__ bsum,
                                                     int M) {
    __shared__ int s[SCAN_BLK];
    int t = threadIdx.x;
    int i = blockIdx.x * SCAN_BLK + t;
    int v = (i < M) ? data[i] : 0;
    s[t] = v;
    __syncthreads();
    for (int off = 1; off < SCAN_BLK; off <<= 1) {
        int add = (t >= off) ? s[t - off] : 0;
        __syncthreads();
        s[t] += add;
        __syncthreads();
    }
    if (i < M) data[i] = s[t] - v + bsum[blockIdx.x];
}

// ---- phase 1c: bucket-grouped scatter (LDS cursors) ---------------------
__global__ __launch_bounds__(256) void k_scatter(const int* __restrict__ src,
                                                 const int* __restrict__ dst,
                                                 const int* __restrict__ hist_s,
                                                 unsigned* __restrict__ bucketed,
                                                 int E, int B, int chunk) {
    __shared__ int cur[MAXB];
    for (int i = threadIdx.x; i < B; i += 256)
        cur[i] = hist_s[i * NP1 + blockIdx.x];
    __syncthreads();
    int e0 = blockIdx.x * chunk;
    int e1 = min(E, e0 + chunk);
    for (int e = e0 + threadIdx.x; e < e1; e += 256) {
        int d = dst[e];
        int p = atomicAdd(&cur[d >> 7], 1);   // LDS atomic
        bucketed[p] = (unsigned)src[e] | ((unsigned)(d & 127) << 17);
    }
}

// ---- per-bucket degree -> dinv ------------------------------------------
__global__ __launch_bounds__(256) void k_deg(const unsigned* __restrict__ bucketed,
                                             const int* __restrict__ hist_s,
                                             float* __restrict__ dinv, int E, int B,
                                             int N) {
    const int b = blockIdx.x;
    const int t = threadIdx.x;
    const int base = hist_s[b * NP1];
    const int endv = (b + 1 < B) ? hist_s[(b + 1) * NP1] : E;
    const int cnt = endv - base;
    __shared__ int h[128];
    if (t < 128) h[t] = 0;
    __syncthreads();
    for (int i = t; i < cnt; i += 256)
        atomicAdd(&h[bucketed[base + i] >> 17], 1);
    __syncthreads();
    int node = (b << 7) + t;
    if (t < 128 && node < N)
        dinv[node] = rsqrtf((float)(h[t] + 1));   // +1 self-loop
}

// ---- MFMA gemm: xs = bf16(dinv * (x @ W)), PERMUTED bf16 layout ---------
// bf16 position p = lid*8 + c  for feature f = c*16 + lid  (p=(f%16)*8+f/16)
__global__ __launch_bounds__(256) void k_gemm(const float* __restrict__ x,
                                              const unsigned short* __restrict__ Wt,
                                              const float* __restrict__ dinv,
                                              unsigned* __restrict__ xs_out, int N) {
    __shared__ short out_lds[4][16][136];
    const int t = threadIdx.x;
    const int wv = t >> 6;
    const int lane = t & 63;
    const int quad = lane >> 4;
    const int lid = lane & 15;
    const int row0 = blockIdx.x * 64;

    int grow = row0 + wv * 16 + lid;
    int growc = grow < N ? grow : N - 1;
    short8 af[4];
#pragma unroll
    for (int q = 0; q < 4; ++q) {
        const float4* xr = (const float4*)(x + (size_t)growc * 128 + q * 32 + quad * 8);
        float4 f0 = xr[0], f1 = xr[1];
        af[q][0] = (short)f2b(f0.x); af[q][1] = (short)f2b(f0.y);
        af[q][2] = (short)f2b(f0.z); af[q][3] = (short)f2b(f0.w);
        af[q][4] = (short)f2b(f1.x); af[q][5] = (short)f2b(f1.y);
        af[q][6] = (short)f2b(f1.z); af[q][7] = (short)f2b(f1.w);
    }

    int drow = row0 + wv * 16 + quad * 4;
    float4 dv4;
    if (drow + 3 < N)      dv4 = *(const float4*)(dinv + drow);
    else {
        dv4.x = dinv[min(drow + 0, N - 1)];
        dv4.y = dinv[min(drow + 1, N - 1)];
        dv4.z = dinv[min(drow + 2, N - 1)];
        dv4.w = dinv[min(drow + 3, N - 1)];
    }

#pragma unroll
    for (int c = 0; c < 8; ++c) {
        f32x4 acc = {0.f, 0.f, 0.f, 0.f};
#pragma unroll
        for (int q = 0; q < 4; ++q) {
            const short8* bp = (const short8*)(Wt + (size_t)(c * 16 + lid) * 128 +
                                               q * 32 + quad * 8);
            acc = __builtin_amdgcn_mfma_f32_16x16x32_bf16(af[q], *bp, acc, 0, 0, 0);
        }
        // permuted position p = lid*8 + c  (feature f = c*16+lid)
        out_lds[wv][quad * 4 + 0][lid * 8 + c] = (short)f2b(acc[0] * dv4.x);
        out_lds[wv][quad * 4 + 1][lid * 8 + c] = (short)f2b(acc[1] * dv4.y);
        out_lds[wv][quad * 4 + 2][lid * 8 + c] = (short)f2b(acc[2] * dv4.z);
        out_lds[wv][quad * 4 + 3][lid * 8 + c] = (short)f2b(acc[3] * dv4.w);
    }
    __syncthreads();

    int rl = lane >> 2;
    int cseg = lane & 3;
    int grow2 = row0 + wv * 16 + rl;
    if (grow2 < N) {
        uint4* dstp = (uint4*)(xs_out + (size_t)grow2 * 64);
        const uint4* srcp = (const uint4*)((const char*)&out_lds[wv][rl][0] + cseg * 64);
#pragma unroll
        for (int tt = 0; tt < 4; ++tt) dstp[cseg * 4 + tt] = srcp[tt];
    }
}

// ---- fused aggregate: one block per bucket, LDS fp32 accumulator --------
// lane roles: grp = lane>>4 (edge slot), sub = lane&15 (uint4 index -> feats
// sub+16j). LDS adds hit 16 consecutive banks per edge (permuted layout).
__global__ __launch_bounds__(1024, 8) void k_agg(const uint4* __restrict__ xs4,
                                                 const unsigned* __restrict__ bucketed,
                                                 const int* __restrict__ hist_s,
                                                 const float* __restrict__ dinv,
                                                 const float* __restrict__ bias,
                                                 float* __restrict__ out,
                                                 int E, int B, int N) {
    __shared__ float acc[128 * 132];
    const int b = blockIdx.x;
    const int t = threadIdx.x;
    const int wv = t >> 6;          // 0..15
    const int lane = t & 63;
    const int grp = lane >> 4;      // edge slot 0..3
    const int sub = lane & 15;      // uint4 index within row
    const int node0 = b << 7;

    const int base = hist_s[b * NP1];
    const int endv = (b + 1 < B) ? hist_s[(b + 1) * NP1] : E;
    const int TT = (endv - base) + 128;   // edges + 128 synthetic self-edges

    for (int i = t; i < 128 * 132; i += 1024) acc[i] = 0.f;
    __syncthreads();

    for (int s0 = wv * 64; s0 < TT; s0 += 1024) {
        int e = s0 + lane;
        unsigned w;
        if (e < 128) {
            int sn = node0 + e;
            if (sn >= N) sn = N - 1;
            w = (unsigned)sn | ((unsigned)e << 17);   // self-edge
        } else {
            w = (e < TT) ? bucketed[base + e - 128] : 0u;
        }

        if (s0 + 64 <= TT) {   // full sweep: static, fully unrolled
#pragma unroll
            for (int g = 0; g < 16; ++g) {
                unsigned we = __shfl(w, g * 4 + grp);
                int srcrow = we & 0x1FFFF;
                int dlow = we >> 17;
                uint4 u = xs4[(size_t)srcrow * 16 + sub];
                float* ar = acc + dlow * 132 + sub;
                atomicAdd(ar + 0,   blo(u.x));
                atomicAdd(ar + 16,  bhi(u.x));
                atomicAdd(ar + 32,  blo(u.y));
                atomicAdd(ar + 48,  bhi(u.y));
                atomicAdd(ar + 64,  blo(u.z));
                atomicAdd(ar + 80,  bhi(u.z));
                atomicAdd(ar + 96,  blo(u.w));
                atomicAdd(ar + 112, bhi(u.w));
            }
        } else {               // tail sweep: masked
            int rem = TT - s0;
            int gmax = (rem + 3) >> 2;
            for (int g = 0; g < gmax; ++g) {
                unsigned we = __shfl(w, g * 4 + grp);
                if (g * 4 + grp < rem) {
                    int srcrow = we & 0x1FFFF;
                    int dlow = we >> 17;
                    uint4 u = xs4[(size_t)srcrow * 16 + sub];
                    float* ar = acc + dlow * 132 + sub;
                    atomicAdd(ar + 0,   blo(u.x));
                    atomicAdd(ar + 16,  bhi(u.x));
                    atomicAdd(ar + 32,  blo(u.y));
                    atomicAdd(ar + 48,  bhi(u.y));
                    atomicAdd(ar + 64,  blo(u.z));
                    atomicAdd(ar + 80,  bhi(u.z));
                    atomicAdd(ar + 96,  blo(u.w));
                    atomicAdd(ar + 112, bhi(u.w));
                }
            }
        }
    }
    __syncthreads();

    // epilogue: thread t -> row r = t>>3, feats h*16 .. h*16+15
    int r = t >> 3;
    int h = t & 7;
    int node = node0 + r;
    if (node < N) {
        float dv = dinv[node];
        const float* ar = acc + r * 132 + h * 16;
        float4* op = (float4*)(out + (size_t)node * 128 + h * 16);
        const float4* bb = (const float4*)(bias + h * 16);
#pragma unroll
        for (int q = 0; q < 4; ++q) {
            float4 a = ((const float4*)ar)[q];
            float4 bq = bb[q];
            float4 o;
            o.x = fmaxf(dv * a.x + bq.x, 0.f);
            o.y = fmaxf(dv * a.y + bq.y, 0.f);
            o.z = fmaxf(dv * a.z + bq.z, 0.f);
            o.w = fmaxf(dv * a.w + bq.w, 0.f);
            op[q] = o;
        }
    }
}

extern "C" void kernel_launch(void* const* d_in, const int* in_sizes, int n_in,
                              void* d_out, int out_size, void* d_ws, size_t ws_size,
                              hipStream_t stream) {
    const float* x   = (const float*)d_in[0];
    const int*   ei  = (const int*)d_in[1];     // [2, E] flat: src then dst
    const float* W   = (const float*)d_in[2];
    const float* b   = (const float*)d_in[3];
    float*       out = (float*)d_out;

    const int N = in_sizes[0] / 128;
    const int E = in_sizes[1] / 2;
    const int* src = ei;
    const int* dst = ei + E;

    const int B = (N + 127) >> 7;            // 782 buckets
    const int M = B * NP1;                   // 125,120 scan entries
    const int chunk = (E + NP1 - 1) / NP1;   // 10,000 edges per phase-1 block

    // workspace carve (256B aligned)
    auto align = [](size_t v) { return (v + 255) & ~(size_t)255; };
    char* p = (char*)d_ws;
    int*            hist     = (int*)p;            p += align((size_t)M * 4);
    int*            bsum     = (int*)p;            p += align(512 * 4);
    float*          dinv     = (float*)p;          p += align((size_t)N * 4);
    unsigned*       bucketed = (unsigned*)p;       p += align((size_t)E * 4);
    unsigned*       xs       = (unsigned*)p;       p += align((size_t)N * 64 * 4);
    unsigned short* Wt       = (unsigned short*)p; p += align(128 * 128 * 2);
    (void)ws_size;

    const int nbM = (M + SCAN_BLK - 1) / SCAN_BLK;   // 489 (<=512 for scanB)

    k_hist   <<<NP1, 256, 0, stream>>>(dst, hist, W, Wt, E, B, chunk);
    k_scanA  <<<nbM, 256, 0, stream>>>(hist, bsum, M);
    k_scanB  <<<1, 512, 0, stream>>>(bsum, nbM);
    k_scanC2 <<<nbM, 256, 0, stream>>>(hist, bsum, M);
    k_scatter<<<NP1, 256, 0, stream>>>(src, dst, hist, bucketed, E, B, chunk);
    k_deg    <<<B, 256, 0, stream>>>(bucketed, hist, dinv, E, B, N);
    k_gemm   <<<(N + 63) / 64, 256, 0, stream>>>(x, Wt, dinv, xs, N);
    k_agg    <<<B, 1024, 0, stream>>>((const uint4*)xs, bucketed, hist, dinv, b,
                                      out, E, B, N);
}